// Round 6
// baseline (142.521 us; speedup 1.0000x reference)
//
#include <hip/hip_runtime.h>

#define T_TOTAL 262144
#define NBLOCKS 1024
#define NMIX 64
#define NDIM 16

typedef short bf16x8 __attribute__((ext_vector_type(8)));
typedef unsigned short u16x8 __attribute__((ext_vector_type(8)));
typedef unsigned short u16x4 __attribute__((ext_vector_type(4)));
typedef float f32x4 __attribute__((ext_vector_type(4)));
typedef unsigned u32x4 __attribute__((ext_vector_type(4)));

__device__ __forceinline__ unsigned short f2bf(float f) {
    union { float f; unsigned u; } v; v.f = f;
    unsigned r = v.u + 0x7fff + ((v.u >> 16) & 1);   // RNE
    return (unsigned short)(r >> 16);
}
__device__ __forceinline__ float bf2f(unsigned short s) {
    union { unsigned u; float f; } v; v.u = ((unsigned)s) << 16;
    return v.f;
}
// HW packed RNE f32->bf16 (same rounding as f2bf; 1 instr per 2 values).
// Operand order (lo=src0) validated on HW: R2's A-path used it and the
// log-like output (which consumes S = A.W) was correct.
__device__ __forceinline__ unsigned cvt_pk(float lo, float hi) {
    unsigned r;
    asm("v_cvt_pk_bf16_f32 %0, %1, %2" : "=v"(r) : "v"(lo), "v"(hi));
    return r;
}
__device__ __forceinline__ float f_lo(unsigned w) {   // bf2f of low half
    union { unsigned u; float f; } v; v.u = w << 16; return v.f;
}
__device__ __forceinline__ float f_hi(unsigned w) {   // bf2f of high half
    union { unsigned u; float f; } v; v.u = w & 0xFFFF0000u; return v.f;
}
// DPP butterfly add within 16-lane rows (xor1, xor2, half-mirror, mirror)
template<int CTRL>
__device__ __forceinline__ float dpp_add(float v) {
    union { float f; int i; } s, t;
    s.f = v;
    t.i = __builtin_amdgcn_update_dpp(0, s.i, CTRL, 0xf, 0xf, true);
    return v + t.f;
}

// last-block reduction state: module memory — NOT touched by harness poison.
// g_count starts 0 (module load) and is reset to 0 by the last block each run.
__device__ float    g_part[NBLOCKS];
__device__ unsigned g_count;

// LDS layout (bytes) — total 22112:
//   L_WH   0      64 rows x 80 B (32 bf16 + pad)            5120
//   L_WL   5120                                              5120
//   L_MUT  10240  16 rows x 144 B (64 bf16 + pad)            2304
//   L_A2   12544  64 f32                                      256
//   L_RED  12800  4 f32 partials + last-block flag at +32      64
//   L_DRED 12864  4 doubles                                    32
//   L_P    12896  4 waves x 16 rows x 144 B                  9216
#define L_WH   0
#define L_WL   5120
#define L_MUT  10240
#define L_A2   12544
#define L_RED  12800
#define L_DRED 12864
#define L_P    12896

__global__ __launch_bounds__(256, 4) void gmm_main(const float* __restrict__ data,
                                                   const float* __restrict__ wghts,
                                                   const float* __restrict__ means,
                                                   const float* __restrict__ dcovs,
                                                   float* __restrict__ out) {
    __shared__ __align__(16) char lds[22112];
    const int tid  = threadIdx.x;
    const int w    = tid >> 6;        // wave id
    const int lane = tid & 63;
    const int gi   = lane & 15;       // fragment row/col index
    const int gq   = lane >> 4;       // fragment quad
    const size_t tblk = (size_t)blockIdx.x * 256;   // 256 points per block

    // ---- phase B: distributed W/MU/A2 prep: 4 threads per mixture ----
    {
        const int m  = tid >> 2;
        const int ql = tid & 3;       // dim-quarter
        const float LOG2E = 1.4426950408889634f;
        const float LOG2_2PI = 2.6514961294723187f;  // log2(6.283185307)
        const float4 d4 = *(const float4*)(dcovs + m * 16 + ql * 4);
        const float4 m4 = *(const float4*)(means + m * 16 + ql * 4);
        const float wm = wghts[m];
        float dc[4] = {d4.x, d4.y, d4.z, d4.w};
        float mu[4] = {m4.x, m4.y, m4.z, m4.w};
        u16x4 ghv, glv, hhv, hlv;
        float sumlog = 0.0f, qsum = 0.0f;
        unsigned short* mut = (unsigned short*)(lds + L_MUT);
#pragma unroll
        for (int j = 0; j < 4; ++j) {
            float pr = __builtin_amdgcn_rcpf(dc[j]);
            float g = -0.5f * LOG2E * pr;     // coeff of x^2
            float h = LOG2E * pr * mu[j];     // coeff of x
            unsigned short gH = f2bf(g), hH = f2bf(h);
            ghv[j] = gH;  glv[j] = f2bf(g - bf2f(gH));
            hhv[j] = hH;  hlv[j] = f2bf(h - bf2f(hH));
            mut[(ql * 4 + j) * 72 + m] = f2bf(mu[j]);
            sumlog += __builtin_amdgcn_logf(dc[j]);   // log2
            qsum   += pr * mu[j] * mu[j];
        }
        char* wrh = lds + L_WH + m * 80;
        char* wrl = lds + L_WL + m * 80;
        *(u16x4*)(wrh + ql * 8)      = ghv;
        *(u16x4*)(wrh + 32 + ql * 8) = hhv;
        *(u16x4*)(wrl + ql * 8)      = glv;
        *(u16x4*)(wrl + 32 + ql * 8) = hlv;
        sumlog += __shfl_xor(sumlog, 1); sumlog += __shfl_xor(sumlog, 2);
        qsum   += __shfl_xor(qsum, 1);   qsum   += __shfl_xor(qsum, 2);
        if (ql == 0) {
            float log2C = __builtin_amdgcn_logf(wm) - 8.0f * LOG2_2PI - 0.5f * sumlog;
            ((float*)(lds + L_A2))[m] = log2C - 0.5f * LOG2E * qsum;
        }
    }
    __syncthreads();   // the ONLY barrier before the epilogue

    // ---- preload B fragments (wave-invariant) ----
    bf16x8 bh[4], bl[4];
    float a2v[4];
#pragma unroll
    for (int c = 0; c < 4; ++c) {
        bh[c] = *(const bf16x8*)(lds + L_WH + (c * 16 + gi) * 80 + gq * 16);
        bl[c] = *(const bf16x8*)(lds + L_WL + (c * 16 + gi) * 80 + gq * 16);
        a2v[c] = ((const float*)(lds + L_A2))[c * 16 + gi];
    }
    bf16x8 mf0 = *(const bf16x8*)(lds + L_MUT + gi * 144 + gq * 16);
    bf16x8 mf1 = *(const bf16x8*)(lds + L_MUT + gi * 144 + 64 + gq * 16);

    char* pbase = lds + L_P + w * 2304;
    float ll_acc = 0.0f;

    // ---- A-fragments direct from global: lane (gi,gq) owns point row
    //      (w*64 + rt*16 + gi), dims (gq&1)*8..+7, squared iff gq<2. ----
    const float* xbase = data + (tblk + (size_t)w * 64 + gi) * 16 + (gq & 1) * 8;
    float4 xa = *(const float4*)(xbase);
    float4 xb = *(const float4*)(xbase + 4);
    const bool sq = (gq < 2);

#pragma unroll
    for (int rt = 0; rt < 4; ++rt) {
        // prefetch next rt's x (full unroll -> SSA, wait lands at next use)
        float4 na, nb;
        if (rt < 3) {
            na = *(const float4*)(xbase + (rt + 1) * 256);
            nb = *(const float4*)(xbase + (rt + 1) * 256 + 4);
        }

        float xv[8] = {xa.x, xa.y, xa.z, xa.w, xb.x, xb.y, xb.z, xb.w};
        u32x4 ahw, alw;
#pragma unroll
        for (int jp = 0; jp < 4; ++jp) {
            float q0 = sq ? xv[2 * jp] * xv[2 * jp]         : xv[2 * jp];
            float q1 = sq ? xv[2 * jp + 1] * xv[2 * jp + 1] : xv[2 * jp + 1];
            unsigned h = cvt_pk(q0, q1);
            ahw[jp] = h;
            alw[jp] = cvt_pk(q0 - f_lo(h), q1 - f_hi(h));
        }
        union { u32x4 wv; bf16x8 hv; } pa, pl;
        pa.wv = ahw;  pl.wv = alw;        // union pun (no TBAA hazard)
        bf16x8 ah = pa.hv;
        bf16x8 al = pl.hv;

        // S = fl*wh + fh*wl + fh*wh  (hi/lo split), 4 column tiles of 16 m.
        // a2 bias folded into the fp32 accumulator init.
        f32x4 pacc[4];
#pragma unroll
        for (int c = 0; c < 4; ++c) {
            f32x4 a = {a2v[c], a2v[c], a2v[c], a2v[c]};
            a = __builtin_amdgcn_mfma_f32_16x16x32_bf16(al, bh[c], a, 0, 0, 0);
            a = __builtin_amdgcn_mfma_f32_16x16x32_bf16(ah, bl[c], a, 0, 0, 0);
            a = __builtin_amdgcn_mfma_f32_16x16x32_bf16(ah, bh[c], a, 0, 0, 0);
            pacc[c] = a;
        }

        // exp2 + row sums (C layout: row = gq*4+reg, col = c*16+gi)
        float p[4][4], prow[4], inv[4];
#pragma unroll
        for (int reg = 0; reg < 4; ++reg) {
#pragma unroll
            for (int c = 0; c < 4; ++c)
                p[c][reg] = __builtin_amdgcn_exp2f(pacc[c][reg]);
            prow[reg] = (p[0][reg] + p[1][reg]) + (p[2][reg] + p[3][reg]);
        }
        // 16-lane reduce over gi via DPP butterflies (VALU pipe)
#pragma unroll
        for (int reg = 0; reg < 4; ++reg) {
            float v = prow[reg];
            v = dpp_add<0xB1>(v);    // quad_perm [1,0,3,2]  : xor 1
            v = dpp_add<0x4E>(v);    // quad_perm [2,3,0,1]  : xor 2
            v = dpp_add<0x141>(v);   // row_half_mirror      : combine quads
            v = dpp_add<0x140>(v);   // row_mirror           : combine octs
            v = fmaxf(v, 1e-35f);
            ll_acc += __builtin_amdgcn_logf(v);       // log2
            inv[reg] = __builtin_amdgcn_rcpf(v);
        }

        // P -> bf16, C layout -> A layout via wave-local LDS tile.
        // Stores through SIGNED short* (same element type as the bf16x8
        // loads below — TBAA-compatible). The only LDS store->load pair in
        // the kernel NOT separated by __syncthreads(); the compiler fence
        // below forbids hoisting the loads above these stores (R2's bug:
        // unsigned-short stores vs signed-short vector loads were treated
        // as non-aliasing and the ds_read was scheduled first -> garbage).
#pragma unroll
        for (int c = 0; c < 4; ++c) {
            unsigned w01 = cvt_pk(p[c][0], p[c][1]);
            unsigned w23 = cvt_pk(p[c][2], p[c][3]);
            char* col = pbase + (c * 16 + gi) * 2;
            *(short*)(col + (gq * 4 + 0) * 144) = (short)(w01 & 0xFFFF);
            *(short*)(col + (gq * 4 + 1) * 144) = (short)(w01 >> 16);
            *(short*)(col + (gq * 4 + 2) * 144) = (short)(w23 & 0xFFFF);
            *(short*)(col + (gq * 4 + 3) * 144) = (short)(w23 >> 16);
        }
        asm volatile("" ::: "memory");   // IR-level store->load fence, 0 instr

        // E = P @ MU  (K=64, 2 k-steps)
        bf16x8 ap0 = *(const bf16x8*)(pbase + gi * 144 + gq * 16);
        bf16x8 ap1 = *(const bf16x8*)(pbase + gi * 144 + 64 + gq * 16);
        f32x4 e = {0.0f, 0.0f, 0.0f, 0.0f};
        e = __builtin_amdgcn_mfma_f32_16x16x32_bf16(ap0, mf0, e, 0, 0, 0);
        e = __builtin_amdgcn_mfma_f32_16x16x32_bf16(ap1, mf1, e, 0, 0, 0);

        size_t trow = tblk + (size_t)w * 64 + rt * 16 + gq * 4;
#pragma unroll
        for (int reg = 0; reg < 4; ++reg)
            out[1 + (trow + reg) * 16 + gi] = e[reg] * inv[reg];

        if (rt < 3) { xa = na; xb = nb; }
    }

    // ---- fused final reduction (replaces gmm_fin): per-block partial to
    //      module-global memory with agent-scope release, done-counter
    //      atomicAdd, last block reduces in double exactly as gmm_fin did. ----
    ll_acc += __shfl_xor(ll_acc, 16);
    ll_acc += __shfl_xor(ll_acc, 32);
    if (lane == 0) ((float*)(lds + L_RED))[w] = ll_acc;
    __syncthreads();
    if (tid == 0) {
        float* r = (float*)(lds + L_RED);
        float s = (r[0] + r[1]) + (r[2] + r[3]);
        __hip_atomic_store(&g_part[blockIdx.x], s, __ATOMIC_RELEASE,
                           __HIP_MEMORY_SCOPE_AGENT);
        unsigned old = __hip_atomic_fetch_add(&g_count, 1u, __ATOMIC_ACQ_REL,
                                              __HIP_MEMORY_SCOPE_AGENT);
        ((unsigned*)(lds + L_RED))[8] = (old == NBLOCKS - 1) ? 1u : 0u;
    }
    __syncthreads();
    if (((volatile unsigned*)(lds + L_RED))[8]) {      // block-uniform
        __threadfence();   // acquire: make all g_part stores visible
        double s = 0.0;
#pragma unroll
        for (int k = 0; k < NBLOCKS / 256; ++k) s += (double)g_part[tid + k * 256];
#pragma unroll
        for (int off = 32; off > 0; off >>= 1) s += __shfl_down(s, off, 64);
        if (lane == 0) ((double*)(lds + L_DRED))[w] = s;
        __syncthreads();
        if (tid == 0) {
            const double LN2 = 0.6931471805599453;
            double* rr = (double*)(lds + L_DRED);
            double tot = (rr[0] + rr[1]) + (rr[2] + rr[3]);
            out[0] = (float)(tot * LN2 / (double)T_TOTAL);
            g_count = 0;   // self-reset for next launch (flushed at kernel end)
        }
    }
}

extern "C" void kernel_launch(void* const* d_in, const int* in_sizes, int n_in,
                              void* d_out, int out_size, void* d_ws, size_t ws_size,
                              hipStream_t stream) {
    const float* data  = (const float*)d_in[0];
    const float* wghts = (const float*)d_in[1];
    const float* means = (const float*)d_in[2];
    const float* dcovs = (const float*)d_in[3];
    float* out  = (float*)d_out;
    (void)d_ws; (void)ws_size;

    gmm_main<<<NBLOCKS, 256, 0, stream>>>(data, wghts, means, dcovs, out);
}

// Round 9
// 80.924 us; speedup vs baseline: 1.7612x; 1.7612x over previous
//
#include <hip/hip_runtime.h>

#define T_TOTAL 262144
#define NBLOCKS 1024
#define NMIX 64
#define NDIM 16

typedef short bf16x8 __attribute__((ext_vector_type(8)));
typedef unsigned short u16x4 __attribute__((ext_vector_type(4)));
typedef float f32x4 __attribute__((ext_vector_type(4)));
typedef unsigned u32x4 __attribute__((ext_vector_type(4)));

__device__ __forceinline__ unsigned short f2bf(float f) {
    union { float f; unsigned u; } v; v.f = f;
    unsigned r = v.u + 0x7fff + ((v.u >> 16) & 1);   // RNE
    return (unsigned short)(r >> 16);
}
__device__ __forceinline__ float bf2f(unsigned short s) {
    union { unsigned u; float f; } v; v.u = ((unsigned)s) << 16;
    return v.f;
}
// HW packed RNE f32->bf16 (same rounding as f2bf; verified on HW in R6 —
// both outputs passed with this on the A and P paths).
__device__ __forceinline__ unsigned cvt_pk(float lo, float hi) {
    unsigned r;
    asm("v_cvt_pk_bf16_f32 %0, %1, %2" : "=v"(r) : "v"(lo), "v"(hi));
    return r;
}
__device__ __forceinline__ float f_lo(unsigned w) {   // bf2f of low half
    union { unsigned u; float f; } v; v.u = w << 16; return v.f;
}
__device__ __forceinline__ float f_hi(unsigned w) {   // bf2f of high half
    union { unsigned u; float f; } v; v.u = w & 0xFFFF0000u; return v.f;
}
// DPP butterfly add within 16-lane rows (verified on HW in R6)
template<int CTRL>
__device__ __forceinline__ float dpp_add(float v) {
    union { float f; int i; } s, t;
    s.f = v;
    t.i = __builtin_amdgcn_update_dpp(0, s.i, CTRL, 0xf, 0xf, true);
    return v + t.f;
}

// EPILOGUE NOTE (R6 lesson): fused last-block reduction with agent-scope
// release/acq_rel atomics cost +53us — each block's ordered atomic emits a
// full L2 writeback (+invalidate) on gfx950's non-coherent per-XCD L2s.
// Plain per-block stores + a second tiny kernel is the fast structure
// (kernel-boundary WB-INV happens ONCE, not 1024x). Measured 82.8us total.

// LDS layout (bytes) — total 22112:
//   L_WH   0      64 rows x 80 B (32 bf16 + pad)            5120
//   L_WL   5120                                              5120
//   L_MUT  10240  16 rows x 144 B (64 bf16 + pad)            2304
//   L_A2   12544  64 f32                                      256
//   L_RED  12800  4 f32 loglike partials                       64
//   L_P    12896  4 waves x 16 rows x 144 B                  9216
#define L_WH   0
#define L_WL   5120
#define L_MUT  10240
#define L_A2   12544
#define L_RED  12800
#define L_P    12896

__global__ __launch_bounds__(256, 4) void gmm_main(const float* __restrict__ data,
                                                   const float* __restrict__ wghts,
                                                   const float* __restrict__ means,
                                                   const float* __restrict__ dcovs,
                                                   float* __restrict__ out,
                                                   float* __restrict__ part) {
    __shared__ __align__(16) char lds[22112];
    const int tid  = threadIdx.x;
    const int w    = tid >> 6;        // wave id
    const int lane = tid & 63;
    const int gi   = lane & 15;       // fragment row/col index
    const int gq   = lane >> 4;       // fragment quad
    const size_t tblk = (size_t)blockIdx.x * 256;   // 256 points per block

    // ---- phase B: distributed W/MU/A2 prep: 4 threads per mixture ----
    {
        const int m  = tid >> 2;
        const int ql = tid & 3;       // dim-quarter
        const float LOG2E = 1.4426950408889634f;
        const float LOG2_2PI = 2.6514961294723187f;  // log2(6.283185307)
        const float4 d4 = *(const float4*)(dcovs + m * 16 + ql * 4);
        const float4 m4 = *(const float4*)(means + m * 16 + ql * 4);
        const float wm = wghts[m];
        float dc[4] = {d4.x, d4.y, d4.z, d4.w};
        float mu[4] = {m4.x, m4.y, m4.z, m4.w};
        u16x4 ghv, glv, hhv, hlv;
        float sumlog = 0.0f, qsum = 0.0f;
        unsigned short* mut = (unsigned short*)(lds + L_MUT);
#pragma unroll
        for (int j = 0; j < 4; ++j) {
            float pr = __builtin_amdgcn_rcpf(dc[j]);
            float g = -0.5f * LOG2E * pr;     // coeff of x^2
            float h = LOG2E * pr * mu[j];     // coeff of x
            unsigned short gH = f2bf(g), hH = f2bf(h);
            ghv[j] = gH;  glv[j] = f2bf(g - bf2f(gH));
            hhv[j] = hH;  hlv[j] = f2bf(h - bf2f(hH));
            mut[(ql * 4 + j) * 72 + m] = f2bf(mu[j]);
            sumlog += __builtin_amdgcn_logf(dc[j]);   // log2
            qsum   += pr * mu[j] * mu[j];
        }
        char* wrh = lds + L_WH + m * 80;
        char* wrl = lds + L_WL + m * 80;
        *(u16x4*)(wrh + ql * 8)      = ghv;
        *(u16x4*)(wrh + 32 + ql * 8) = hhv;
        *(u16x4*)(wrl + ql * 8)      = glv;
        *(u16x4*)(wrl + 32 + ql * 8) = hlv;
        sumlog += __shfl_xor(sumlog, 1); sumlog += __shfl_xor(sumlog, 2);
        qsum   += __shfl_xor(qsum, 1);   qsum   += __shfl_xor(qsum, 2);
        if (ql == 0) {
            float log2C = __builtin_amdgcn_logf(wm) - 8.0f * LOG2_2PI - 0.5f * sumlog;
            ((float*)(lds + L_A2))[m] = log2C - 0.5f * LOG2E * qsum;
        }
    }
    __syncthreads();   // the ONLY barrier before the epilogue

    // ---- preload B fragments (wave-invariant) ----
    bf16x8 bh[4], bl[4];
    float a2v[4];
#pragma unroll
    for (int c = 0; c < 4; ++c) {
        bh[c] = *(const bf16x8*)(lds + L_WH + (c * 16 + gi) * 80 + gq * 16);
        bl[c] = *(const bf16x8*)(lds + L_WL + (c * 16 + gi) * 80 + gq * 16);
        a2v[c] = ((const float*)(lds + L_A2))[c * 16 + gi];
    }
    bf16x8 mf0 = *(const bf16x8*)(lds + L_MUT + gi * 144 + gq * 16);
    bf16x8 mf1 = *(const bf16x8*)(lds + L_MUT + gi * 144 + 64 + gq * 16);

    char* pbase = lds + L_P + w * 2304;
    float ll_acc = 0.0f;

    // ---- A-fragments direct from global: lane (gi,gq) owns point row
    //      (w*64 + rt*16 + gi), dims (gq&1)*8..+7, squared iff gq<2. ----
    const float* xbase = data + (tblk + (size_t)w * 64 + gi) * 16 + (gq & 1) * 8;
    float4 xa = *(const float4*)(xbase);
    float4 xb = *(const float4*)(xbase + 4);
    const bool sq = (gq < 2);

#pragma unroll
    for (int rt = 0; rt < 4; ++rt) {
        // prefetch next rt's x (full unroll -> SSA, wait lands at next use)
        float4 na, nb;
        if (rt < 3) {
            na = *(const float4*)(xbase + (rt + 1) * 256);
            nb = *(const float4*)(xbase + (rt + 1) * 256 + 4);
        }

        float xv[8] = {xa.x, xa.y, xa.z, xa.w, xb.x, xb.y, xb.z, xb.w};
        u32x4 ahw, alw;
#pragma unroll
        for (int jp = 0; jp < 4; ++jp) {
            float q0 = sq ? xv[2 * jp] * xv[2 * jp]         : xv[2 * jp];
            float q1 = sq ? xv[2 * jp + 1] * xv[2 * jp + 1] : xv[2 * jp + 1];
            unsigned h = cvt_pk(q0, q1);
            ahw[jp] = h;
            alw[jp] = cvt_pk(q0 - f_lo(h), q1 - f_hi(h));
        }
        union { u32x4 wv; bf16x8 hv; } pa, pl;
        pa.wv = ahw;  pl.wv = alw;        // union pun (no TBAA hazard)
        bf16x8 ah = pa.hv;
        bf16x8 al = pl.hv;

        // S = fl*wh + fh*wl + fh*wh  (hi/lo split), 4 column tiles of 16 m.
        // a2 bias folded into the fp32 accumulator init.
        f32x4 pacc[4];
#pragma unroll
        for (int c = 0; c < 4; ++c) {
            f32x4 a = {a2v[c], a2v[c], a2v[c], a2v[c]};
            a = __builtin_amdgcn_mfma_f32_16x16x32_bf16(al, bh[c], a, 0, 0, 0);
            a = __builtin_amdgcn_mfma_f32_16x16x32_bf16(ah, bl[c], a, 0, 0, 0);
            a = __builtin_amdgcn_mfma_f32_16x16x32_bf16(ah, bh[c], a, 0, 0, 0);
            pacc[c] = a;
        }

        // exp2 + row sums (C layout: row = gq*4+reg, col = c*16+gi)
        float p[4][4], prow[4], inv[4];
#pragma unroll
        for (int reg = 0; reg < 4; ++reg) {
#pragma unroll
            for (int c = 0; c < 4; ++c)
                p[c][reg] = __builtin_amdgcn_exp2f(pacc[c][reg]);
            prow[reg] = (p[0][reg] + p[1][reg]) + (p[2][reg] + p[3][reg]);
        }
        // 16-lane reduce over gi via DPP butterflies (VALU pipe)
#pragma unroll
        for (int reg = 0; reg < 4; ++reg) {
            float v = prow[reg];
            v = dpp_add<0xB1>(v);    // quad_perm [1,0,3,2]  : xor 1
            v = dpp_add<0x4E>(v);    // quad_perm [2,3,0,1]  : xor 2
            v = dpp_add<0x141>(v);   // row_half_mirror      : combine quads
            v = dpp_add<0x140>(v);   // row_mirror           : combine octs
            v = fmaxf(v, 1e-35f);
            ll_acc += __builtin_amdgcn_logf(v);       // log2
            inv[reg] = __builtin_amdgcn_rcpf(v);
        }

        // P -> bf16, C layout -> A layout via wave-local LDS tile.
        // SIGNED short stores (TBAA-matches the bf16x8 loads) + zero-cost
        // compiler fence: forbids hoisting the ds_read above these stores
        // (R2's miscompile). Verified correct on HW in R6.
#pragma unroll
        for (int c = 0; c < 4; ++c) {
            unsigned w01 = cvt_pk(p[c][0], p[c][1]);
            unsigned w23 = cvt_pk(p[c][2], p[c][3]);
            char* col = pbase + (c * 16 + gi) * 2;
            *(short*)(col + (gq * 4 + 0) * 144) = (short)(w01 & 0xFFFF);
            *(short*)(col + (gq * 4 + 1) * 144) = (short)(w01 >> 16);
            *(short*)(col + (gq * 4 + 2) * 144) = (short)(w23 & 0xFFFF);
            *(short*)(col + (gq * 4 + 3) * 144) = (short)(w23 >> 16);
        }
        asm volatile("" ::: "memory");   // IR-level store->load fence, 0 instr

        // E = P @ MU  (K=64, 2 k-steps)
        bf16x8 ap0 = *(const bf16x8*)(pbase + gi * 144 + gq * 16);
        bf16x8 ap1 = *(const bf16x8*)(pbase + gi * 144 + 64 + gq * 16);
        f32x4 e = {0.0f, 0.0f, 0.0f, 0.0f};
        e = __builtin_amdgcn_mfma_f32_16x16x32_bf16(ap0, mf0, e, 0, 0, 0);
        e = __builtin_amdgcn_mfma_f32_16x16x32_bf16(ap1, mf1, e, 0, 0, 0);

        size_t trow = tblk + (size_t)w * 64 + rt * 16 + gq * 4;
#pragma unroll
        for (int reg = 0; reg < 4; ++reg)
            out[1 + (trow + reg) * 16 + gi] = e[reg] * inv[reg];

        if (rt < 3) { xa = na; xb = nb; }
    }

    // ---- per-block loglike partial: plain store to distinct address.
    //      Kernel-boundary L2 WB-INV makes these visible to gmm_fin. ----
    ll_acc += __shfl_xor(ll_acc, 16);
    ll_acc += __shfl_xor(ll_acc, 32);
    if (lane == 0) ((float*)(lds + L_RED))[w] = ll_acc;
    __syncthreads();
    if (tid == 0) {
        float* r = (float*)(lds + L_RED);
        part[blockIdx.x] = (r[0] + r[1]) + (r[2] + r[3]);
    }
}

__global__ void gmm_fin(const float* __restrict__ part, float* __restrict__ out) {
    __shared__ double red[4];
    const int tid = threadIdx.x;
    double s = 0.0;
#pragma unroll
    for (int k = 0; k < NBLOCKS / 256; ++k) s += (double)part[tid + k * 256];
#pragma unroll
    for (int off = 32; off > 0; off >>= 1) s += __shfl_down(s, off, 64);
    const int wv = tid >> 6, lane = tid & 63;
    if (lane == 0) red[wv] = s;
    __syncthreads();
    if (tid == 0) {
        const double LN2 = 0.6931471805599453;
        double tot = (red[0] + red[1]) + (red[2] + red[3]);
        out[0] = (float)(tot * LN2 / (double)T_TOTAL);
    }
}

extern "C" void kernel_launch(void* const* d_in, const int* in_sizes, int n_in,
                              void* d_out, int out_size, void* d_ws, size_t ws_size,
                              hipStream_t stream) {
    const float* data  = (const float*)d_in[0];
    const float* wghts = (const float*)d_in[1];
    const float* means = (const float*)d_in[2];
    const float* dcovs = (const float*)d_in[3];
    float* out  = (float*)d_out;
    float* part = (float*)d_ws;   // 1024 fp32 partials (distinct addresses)

    gmm_main<<<NBLOCKS, 256, 0, stream>>>(data, wghts, means, dcovs, out, part);
    gmm_fin<<<1, 256, 0, stream>>>(part, out);
}